// Round 6
// baseline (1439.661 us; speedup 1.0000x reference)
//
#include <hip/hip_runtime.h>

// Fused 2-layer LSTM (B=4096, S=512, H=64) + dense(64->32 relu)->dense(32->24).
// R6: 4 waves/SIMD. 128 WGs x 32 batch rows x 1024 thr (16 waves), 1 WG/CU on
// 128 CUs (128 idle — deliberate: R3/R4/R5 all pinned at 2077 cyc/step with
// 2 waves/SIMD under three different sync schemes => fine-grained dependency
// stalls, fixable only by more independent streams per SIMD).
// Waves: is2 = wave>>3 (layer), rg = (wave>>2)&1 (row-group), ct = wave&3
// (col-tile). Per-wave work identical to R3's 443 us kernel.
// Single barrier/step, parity-2 LDS rings, layer-2 delayed one step:
// z2[t-1] = b2 + Wih2@h1[t-1] + Whh2@h2[t-2].

typedef __attribute__((ext_vector_type(8))) short bf16x8;
typedef __attribute__((ext_vector_type(4))) float floatx4;

#define SEQ 512
#define HID 64
#define ROWS 32
#define LOG2E 1.4426950408889634f

__device__ inline floatx4 MFMA(bf16x8 a, bf16x8 b, floatx4 c) {
    return __builtin_amdgcn_mfma_f32_16x16x32_bf16(a, b, c, 0, 0, 0);
}
__device__ inline short f2bf(float f) {
    __bf16 b = (__bf16)f;
    return __builtin_bit_cast(short, b);
}
__device__ inline float exp2_fast(float x) {
#if __has_builtin(__builtin_amdgcn_exp2f)
    return __builtin_amdgcn_exp2f(x);
#else
    return __expf(x * 0.6931471805599453f);
#endif
}
__device__ inline float rcp_fast(float x) { return __builtin_amdgcn_rcpf(x); }

// z* pre-scaled: zi=-i*log2e, zf=-f*log2e, zg=-2g*log2e, zo=-o*log2e.
// 5 exp + 2 rcp per element.
__device__ inline float lstm_gate(float zi, float zf, float zg, float zo, float& c) {
    float ei = exp2_fast(zi);
    float ef = exp2_fast(zf);
    float eg = exp2_fast(zg);
    float eo = exp2_fast(zo);
    float P  = (1.0f + ei) * (1.0f + eg);
    float F  = 1.0f + ef;
    float num = c * P + (1.0f - eg) * F;
    c = num * rcp_fast(P * F);
    float ec = exp2_fast(fminf(c * (-2.0f * LOG2E), 40.0f));
    return (1.0f - ec) * rcp_fast((1.0f + eo) * (1.0f + ec));
}

__global__ __launch_bounds__(1024, 1) void lstm_fused(
    const float* __restrict__ x,
    const float* __restrict__ Wih1, const float* __restrict__ Whh1,
    const float* __restrict__ bih1, const float* __restrict__ bhh1,
    const float* __restrict__ Wih2, const float* __restrict__ Whh2,
    const float* __restrict__ bih2, const float* __restrict__ bhh2,
    const float* __restrict__ Wd1,  const float* __restrict__ bd1,
    const float* __restrict__ Wd2,  const float* __restrict__ bd2,
    float* __restrict__ out)
{
    const int tid  = threadIdx.x;
    const int wave = tid >> 6;
    const int ct   = wave & 3;        // column-tile (h-cols [16ct,16ct+16))
    const int rg   = (wave >> 2) & 1; // row-group (batch rows [16rg,16rg+16))
    const int is2  = wave >> 3;       // 0: layer-1 wave, 1: layer-2 wave
    const int lane = tid & 63;
    const int l15  = lane & 15;
    const int quad = lane >> 4;
    const int b0   = blockIdx.x * ROWS;

    __shared__ __align__(16) float x_s[ROWS][516];      // 66 KB
    __shared__ __align__(16) short h1_s[2][ROWS][72];   // parity ring, 9 KB
    __shared__ __align__(16) short h2_s[2][ROWS][72];
    __shared__ float y1_s[ROWS][32];

    // ---- stage x tile (32 rows x 512 f32) ----
    {
        const int row = tid >> 5;
        const int c0  = (tid & 31) * 16;
        const float4* src = reinterpret_cast<const float4*>(x + (size_t)(b0 + row) * SEQ + c0);
        float4* dst = reinterpret_cast<float4*>(&x_s[row][c0]);
        #pragma unroll
        for (int j = 0; j < 4; ++j) dst[j] = src[j];
    }
    for (int i = tid; i < 2 * ROWS * 72; i += 1024) {   // zero both parities
        (&h1_s[0][0][0])[i] = 0;
        (&h2_s[0][0][0])[i] = 0;
    }

    // ---- per-wave weight B-fragments (pre-scaled by -log2e; gate g: -2log2e) ----
    // L1 waves: Wf[0..1] = Whh1 K-halves. L2 waves: Wf[0..1]=Wih2, Wf[2..3]=Whh2.
    bf16x8 Wf[4][4];
    float wxc[4], bcs[4];
    #pragma unroll
    for (int g = 0; g < 4; ++g) {
        const float sc = (g == 2) ? (-2.0f * LOG2E) : (-LOG2E);
        const int col = g * 64 + ct * 16 + l15;
        if (!is2) {
            wxc[g] = Wih1[col] * sc;
            bcs[g] = (bih1[col] + bhh1[col]) * sc;
        } else {
            wxc[g] = 0.0f;
            bcs[g] = (bih2[col] + bhh2[col]) * sc;
        }
        #pragma unroll
        for (int kt = 0; kt < 2; ++kt) {
            const int koff = kt * 32 + quad * 8;
            union { short s[8]; bf16x8 v; } u0, u1;
            #pragma unroll
            for (int j = 0; j < 8; ++j) {
                if (!is2) {
                    u0.s[j] = f2bf(Whh1[col * HID + koff + j] * sc);
                    u1.s[j] = 0;
                } else {
                    u0.s[j] = f2bf(Wih2[col * HID + koff + j] * sc);
                    u1.s[j] = f2bf(Whh2[col * HID + koff + j] * sc);
                }
            }
            Wf[kt][g] = u0.v;
            Wf[2 + kt][g] = u1.v;
        }
    }

    const int hcol = ct * 16 + l15;
    const int arow = rg * 16 + l15;           // A-frag LDS row for this wave
    const int wrow = rg * 16 + quad * 4;      // h-write base row
    float cst[4] = {0, 0, 0, 0};

    __syncthreads();   // x staged, rings zeroed

    #pragma unroll 2
    for (int t = 0; t < SEQ; ++t) {
        const int pr1 = (t + 1) & 1;   // holds h1[t-1] / receives h2[t-1]
        const int pr2 = t & 1;         // holds h2[t-2] / receives h1[t]
        __syncthreads();
        if (!is2) {
            const bf16x8 A1a = *reinterpret_cast<const bf16x8*>(&h1_s[pr1][arow][quad * 8]);
            const bf16x8 A1b = *reinterpret_cast<const bf16x8*>(&h1_s[pr1][arow][32 + quad * 8]);
            floatx4 z[4];
            #pragma unroll
            for (int g = 0; g < 4; ++g)
                #pragma unroll
                for (int r = 0; r < 4; ++r)
                    z[g][r] = x_s[wrow + r][t] * wxc[g] + bcs[g];
            #pragma unroll
            for (int g = 0; g < 4; ++g) {
                z[g] = MFMA(A1a, Wf[0][g], z[g]);
                z[g] = MFMA(A1b, Wf[1][g], z[g]);
            }
            #pragma unroll
            for (int r = 0; r < 4; ++r) {
                float hv = lstm_gate(z[0][r], z[1][r], z[2][r], z[3][r], cst[r]);
                h1_s[pr2][wrow + r][hcol] = f2bf(hv);
            }
        } else {
            const bf16x8 A1a = *reinterpret_cast<const bf16x8*>(&h1_s[pr1][arow][quad * 8]);
            const bf16x8 A1b = *reinterpret_cast<const bf16x8*>(&h1_s[pr1][arow][32 + quad * 8]);
            const bf16x8 A2a = *reinterpret_cast<const bf16x8*>(&h2_s[pr2][arow][quad * 8]);
            const bf16x8 A2b = *reinterpret_cast<const bf16x8*>(&h2_s[pr2][arow][32 + quad * 8]);
            floatx4 z[4];
            #pragma unroll
            for (int g = 0; g < 4; ++g)
                z[g] = floatx4{bcs[g], bcs[g], bcs[g], bcs[g]};
            #pragma unroll
            for (int g = 0; g < 4; ++g) {
                z[g] = MFMA(A1a, Wf[0][g], z[g]);   // Wih2 @ h1[t-1]
                z[g] = MFMA(A1b, Wf[1][g], z[g]);
                z[g] = MFMA(A2a, Wf[2][g], z[g]);   // Whh2 @ h2[t-2]
                z[g] = MFMA(A2b, Wf[3][g], z[g]);
            }
            const float m2 = (t == 0) ? 0.0f : 1.0f;  // discard bogus step at t=0
            #pragma unroll
            for (int r = 0; r < 4; ++r) {
                float cc = cst[r];
                float hv = lstm_gate(z[0][r], z[1][r], z[2][r], z[3][r], cc) * m2;
                cst[r] = cc * m2;
                h2_s[pr1][wrow + r][hcol] = f2bf(hv);  // h2[t-1]
            }
        }
    }

    // ---- drain: layer 2 for t = SEQ-1 (layer-2 waves only) ----
    __syncthreads();
    if (is2) {
        const bf16x8 A1a = *reinterpret_cast<const bf16x8*>(&h1_s[1][arow][quad * 8]);      // h1[S-1]
        const bf16x8 A1b = *reinterpret_cast<const bf16x8*>(&h1_s[1][arow][32 + quad * 8]);
        const bf16x8 A2a = *reinterpret_cast<const bf16x8*>(&h2_s[0][arow][quad * 8]);      // h2[S-2]
        const bf16x8 A2b = *reinterpret_cast<const bf16x8*>(&h2_s[0][arow][32 + quad * 8]);
        floatx4 z[4];
        #pragma unroll
        for (int g = 0; g < 4; ++g) {
            z[g] = floatx4{bcs[g], bcs[g], bcs[g], bcs[g]};
            z[g] = MFMA(A1a, Wf[0][g], z[g]);
            z[g] = MFMA(A1b, Wf[1][g], z[g]);
            z[g] = MFMA(A2a, Wf[2][g], z[g]);
            z[g] = MFMA(A2b, Wf[3][g], z[g]);
        }
        float* h2f = &x_s[0][0];               // repurpose x stage as [32][64] f32
        #pragma unroll
        for (int r = 0; r < 4; ++r) {
            float cc = cst[r];
            h2f[(wrow + r) * HID + hcol] = lstm_gate(z[0][r], z[1][r], z[2][r], z[3][r], cc);
        }
    }
    __syncthreads();

    // ---- epilogue: relu(h2 @ Wd1^T + bd1) @ Wd2^T + bd2 ----
    const float* h2f = &x_s[0][0];
    for (int idx = tid; idx < ROWS * 32; idx += 1024) {
        const int b = idx >> 5, o = idx & 31;
        float acc = bd1[o];
        #pragma unroll 8
        for (int k = 0; k < HID; ++k) acc += h2f[b * HID + k] * Wd1[o * HID + k];
        y1_s[b][o] = fmaxf(acc, 0.0f);
    }
    __syncthreads();
    for (int idx = tid; idx < ROWS * 24; idx += 1024) {
        const int b = idx / 24, o = idx - b * 24;
        float acc = bd2[o];
        #pragma unroll 8
        for (int k = 0; k < 32; ++k) acc += y1_s[b][k] * Wd2[o * 32 + k];
        out[(size_t)(b0 + b) * 24 + o] = acc;
    }
}

extern "C" void kernel_launch(void* const* d_in, const int* in_sizes, int n_in,
                              void* d_out, int out_size, void* d_ws, size_t ws_size,
                              hipStream_t stream) {
    const float* x    = (const float*)d_in[0];
    const float* Wih1 = (const float*)d_in[1];
    const float* Whh1 = (const float*)d_in[2];
    const float* bih1 = (const float*)d_in[3];
    const float* bhh1 = (const float*)d_in[4];
    const float* Wih2 = (const float*)d_in[5];
    const float* Whh2 = (const float*)d_in[6];
    const float* bih2 = (const float*)d_in[7];
    const float* bhh2 = (const float*)d_in[8];
    const float* Wd1  = (const float*)d_in[9];
    const float* bd1  = (const float*)d_in[10];
    const float* Wd2  = (const float*)d_in[11];
    const float* bd2  = (const float*)d_in[12];
    float* out = (float*)d_out;

    lstm_fused<<<128, 1024, 0, stream>>>(x, Wih1, Whh1, bih1, bhh1,
                                         Wih2, Whh2, bih2, bhh2,
                                         Wd1, bd1, Wd2, bd2, out);
}